// Round 11
// baseline (151.682 us; speedup 1.0000x reference)
//
#include <hip/hip_runtime.h>
#include <math.h>

#define DIM 128
#define KCODES 1024
#define NROWS 65536

typedef short bf16x8 __attribute__((ext_vector_type(8)));
typedef float f32x4 __attribute__((ext_vector_type(4)));

// ---- workspace float-index layout ----
#define WS_COUNTS 0        // 1024 f: batch histogram (zeroed by k_prep)
#define WS_ESUM   1024     // 131072 f: segment sums (zeroed by k_prep)
#define WS_IOFF   132096   // 1024 int: per-code allocation cursor (zeroed by k_prep)
#define WS_TOTAL  133120   // 1 f
#define WS_ENORM2 133124   // 1024 f: 512 - 0.5*||e||^2
#define WS_EBF    134148   // 131072 bf16 (= 65536 float slots), 16B aligned, PRE-SWIZZLED
#define WS_WIN    461828   // 65536 int
#define WS_SORTED 527364   // 65536 int
#define WS_SCODE  592900   // 65536 int

// ---- output float layout ----
#define OFF_Q   0
#define OFF_IND 8388608
#define OFF_NCS 8454144
#define OFF_NEA 8455168
#define OFF_NE  8586240

// Round-11 note: this is the round-9 kernel, reverted verbatim after the
// round-10 single-cooperative-kernel experiment FAILED correctness (absmax
// 1024 on embed_ind): under the harness's graph capture, a captured
// hipLaunchCooperativeKernel grid.sync did not provide a reliable cross-XCD
// release/acquire chain for ebf (written by phase P on one XCD, consumed by
// global_load_lds DMA on another). The inter-kernel dispatch boundary IS the
// coherence mechanism; keep the 5-dispatch structure.
// Session ledger: k_fused pinned at ~49.7us across 4 structural staging
// variants; tails at atomic/BW floors; ~43us harness poison-fill untouchable.

static __device__ __forceinline__ unsigned short f2bf(float f) {
    unsigned u = __float_as_uint(f);
    unsigned r = (u + 0x7FFFu + ((u >> 16) & 1u)) >> 16;  // RTN-even
    return (unsigned short)r;
}

// direct global->LDS DMA, 16B per lane (dest = wave-uniform base + lane*16)
static __device__ __forceinline__ void gload_lds16(const unsigned short* g,
                                                   unsigned short* l) {
    __builtin_amdgcn_global_load_lds(
        (const __attribute__((address_space(1))) void*)g,
        (__attribute__((address_space(3))) void*)l, 16, 0, 0);
}

// ============ kernel 1: embed -> PRE-SWIZZLED bf16 copy + half-norms + zeroing ============
__global__ __launch_bounds__(64) void k_prep(const float* __restrict__ embed,
                                             unsigned short* __restrict__ ebf,
                                             float* __restrict__ en2,
                                             float* __restrict__ counts,
                                             float* __restrict__ esum,
                                             int* __restrict__ cursor) {
    int k = blockIdx.x;
    int l = threadIdx.x;
    if (l == 0) { counts[k] = 0.0f; cursor[k] = 0; }
    *(float2*)&esum[(size_t)k * DIM + l * 2] = (float2){0.0f, 0.0f};
    float2 v = *(const float2*)&embed[(size_t)k * DIM + l * 2];
    ushort2 b;
    b.x = f2bf(v.x);
    b.y = f2bf(v.y);
    *(ushort2*)&ebf[(k * DIM + l * 2) ^ ((k & 7) << 3)] = b;
    float s = v.x * v.x + v.y * v.y;
    #pragma unroll
    for (int off = 32; off; off >>= 1) s += __shfl_xor(s, off);
    if (l == 0) en2[k] = 512.0f - 0.5f * s;
}

// ============ kernel 2: fused scoring + rescore + hist + quantize ============
// 128-row blocks, grid 512 = 2 blk/CU, 4 waves/SIMD. DMA e-tile staging
// (pre-swizzled ebf -> linear LDS dest + swizzled fragment reads). fp32
// exact-difference rescore (verified safe: reference's own fp32 norm-trick
// error ~2e-3 >> exact-diff error ~2e-4; absmax unchanged vs fp64).
__global__ __launch_bounds__(512, 4) void k_fused(const float* __restrict__ x,
                                                  const float* __restrict__ embed,
                                                  const unsigned short* __restrict__ ebf,
                                                  const float* __restrict__ en2g,
                                                  int* __restrict__ win_g,
                                                  float* __restrict__ counts,
                                                  float* __restrict__ out) {
    __shared__ unsigned short buf[2][128 * 128];  // ping-pong; buf[0] stages x first
    __shared__ float en2s[KCODES];
    __shared__ int winS[128];

    const int tid = threadIdx.x;  // 0..511
    const int row0 = blockIdx.x * 128;

    #pragma unroll
    for (int i = 0; i < 2; ++i) en2s[i * 512 + tid] = en2g[i * 512 + tid];

    // ---- stage x tile (fp32 -> bf16) into buf[0], swizzled ----
    #pragma unroll
    for (int i = 0; i < 8; ++i) {
        int idx4 = i * 512 + tid;
        int lin = idx4 * 4;
        int r = lin >> 7, d = lin & 127;
        float4 v = *(const float4*)&x[(size_t)(row0 + r) * DIM + d];
        ushort4 b;
        b.x = f2bf(v.x); b.y = f2bf(v.y); b.z = f2bf(v.z); b.w = f2bf(v.w);
        *(ushort4*)&buf[0][(r * 128 + d) ^ ((r & 7) << 3)] = b;
    }
    __syncthreads();  // x tile visible

    const int lane = tid & 63;
    const int wv = tid >> 6;        // 0..7
    const int ch = wv & 1;          // code half (64 codes)
    const int rh = (wv >> 1) * 32;  // row base (32 rows per wave)
    const int l15 = lane & 15;
    const int q = lane >> 4;
    const int swz = (l15 & 7) << 3;  // fragment-row swizzle

    // ---- issue tile0 DMA into buf[1] (pre-swizzled source -> linear dest) ----
    #pragma unroll
    for (int i = 0; i < 4; ++i) {
        int idx8 = i * 512 + tid;
        gload_lds16(&ebf[idx8 * 8], &buf[1][idx8 * 8]);
    }

    // ---- hoist A-fragments (ct-invariant) from buf[0] ----
    bf16x8 af[4][2];  // [ks][rt]
    #pragma unroll
    for (int ks = 0; ks < 4; ++ks)
        #pragma unroll
        for (int t = 0; t < 2; ++t)
            af[ks][t] = *(const bf16x8*)&buf[0][((rh + t * 16 + l15) * 128 + ks * 32 + q * 8) ^ swz];
    __syncthreads();  // tile0 DMA drained + af reads complete

    float m1[2][4], m2[2][4];
    #pragma unroll
    for (int a = 0; a < 2; ++a)
        #pragma unroll
        for (int b = 0; b < 4; ++b) { m1[a][b] = 0.0f; m2[a][b] = 0.0f; }

    for (int ct = 0; ct < 8; ++ct) {
        const int c0 = ct * 128;
        const unsigned short* cbuf = buf[1 ^ (ct & 1)];  // tile ct lives here

        // issue next-tile DMA into the buffer whose reads ended at the prev barrier
        if (ct < 7) {
            unsigned short* nbuf = buf[ct & 1];
            const unsigned short* gsrc = ebf + (size_t)(c0 + 128) * DIM;
            #pragma unroll
            for (int i = 0; i < 4; ++i) {
                int idx8 = i * 512 + tid;
                gload_lds16(&gsrc[idx8 * 8], &nbuf[idx8 * 8]);
            }
        }

        // C-init = en2 (folds norm add into MFMA)
        f32x4 acc[2][4];
        #pragma unroll
        for (int cl = 0; cl < 4; ++cl) {
            float en = en2s[c0 + ch * 64 + cl * 16 + l15];
            #pragma unroll
            for (int rt = 0; rt < 2; ++rt) acc[rt][cl] = (f32x4){en, en, en, en};
        }

        __builtin_amdgcn_s_setprio(1);
        #pragma unroll
        for (int ks = 0; ks < 4; ++ks) {
            bf16x8 bfr[4];
            #pragma unroll
            for (int cl = 0; cl < 4; ++cl)
                bfr[cl] = *(const bf16x8*)&cbuf[((ch * 64 + cl * 16 + l15) * 128 + ks * 32 + q * 8) ^ swz];
            #pragma unroll
            for (int rt = 0; rt < 2; ++rt)
                #pragma unroll
                for (int cl = 0; cl < 4; ++cl)
                    acc[rt][cl] = __builtin_amdgcn_mfma_f32_16x16x32_bf16(af[ks][rt], bfr[cl],
                                                                          acc[rt][cl], 0, 0, 0);
        }

        // pairwise top-2 tracking: 5 ops / 2 values
        #pragma unroll
        for (int cp = 0; cp < 2; ++cp) {
            unsigned cu0 = (unsigned)(c0 + ch * 64 + cp * 32 + l15);
            unsigned cu1 = cu0 + 16u;
            #pragma unroll
            for (int rt = 0; rt < 2; ++rt)
                #pragma unroll
                for (int rg = 0; rg < 4; ++rg) {
                    float sa = acc[rt][cp * 2][rg];
                    float sb = acc[rt][cp * 2 + 1][rg];
                    float a = __uint_as_float((__float_as_uint(sa) & ~1023u) | cu0);
                    float b = __uint_as_float((__float_as_uint(sb) & ~1023u) | cu1);
                    m2[rt][rg] = fmaxf(m2[rt][rg],
                                       __builtin_amdgcn_fmed3f(a, b, m1[rt][rg]));
                    m1[rt][rg] = fmaxf(fmaxf(a, b), m1[rt][rg]);
                }
        }
        __builtin_amdgcn_s_setprio(0);

        __syncthreads();  // DMA drained (vmcnt) + this tile's reads complete
    }

    // buf free: floats [0,512) = merge scratch, [512,1536) = histogram
    float* scratch = (float*)buf[0];
    unsigned* hist = (unsigned*)buf[0] + 512;

    #pragma unroll
    for (int rt = 0; rt < 2; ++rt)
        #pragma unroll
        for (int rg = 0; rg < 4; ++rg) {
            float a1 = m1[rt][rg], a2 = m2[rt][rg];
            #pragma unroll
            for (int off = 1; off <= 8; off <<= 1) {
                float o1 = __shfl_xor(a1, off);
                float o2 = __shfl_xor(a2, off);
                float t = fmaxf(a2, o2);
                a2 = __builtin_amdgcn_fmed3f(a1, o1, t);
                a1 = fmaxf(a1, o1);
            }
            if (l15 == 0) {
                int row = rh + rt * 16 + q * 4 + rg;
                scratch[row * 4 + ch * 2 + 0] = a1;
                scratch[row * 4 + ch * 2 + 1] = a2;
            }
        }

    #pragma unroll
    for (int i = 0; i < 2; ++i) hist[i * 512 + tid] = 0u;
    __syncthreads();  // S1: scratch + hist-zero visible

    // ---- fp32 exact-difference rescore: 16 lanes/row ----
    {
        const int sub = tid & 15;
        const int g = tid >> 4;  // 0..31
        #pragma unroll 2
        for (int rr = 0; rr < 4; ++rr) {
            const int lrow = g * 4 + rr;
            const float* sp = &scratch[lrow * 4];
            int ci[4];
            ci[0] = (int)(__float_as_uint(sp[0]) & 1023u);
            ci[1] = (int)(__float_as_uint(sp[1]) & 1023u);
            ci[2] = (int)(__float_as_uint(sp[2]) & 1023u);
            ci[3] = (int)(__float_as_uint(sp[3]) & 1023u);

            const float* xr = &x[(size_t)(row0 + lrow) * DIM + sub * 4];
            float4 xa = *(const float4*)xr;
            float4 xb = *(const float4*)(xr + 64);

            float d[4];
            #pragma unroll
            for (int j = 0; j < 4; ++j) {
                const float* er2 = &embed[(size_t)ci[j] * DIM + sub * 4];
                float4 ea4 = *(const float4*)er2;
                float4 eb4 = *(const float4*)(er2 + 64);
                float t0 = xa.x - ea4.x;
                float t1 = xa.y - ea4.y;
                float t2 = xa.z - ea4.z;
                float t3 = xa.w - ea4.w;
                float t4 = xb.x - eb4.x;
                float t5 = xb.y - eb4.y;
                float t6 = xb.z - eb4.z;
                float t7 = xb.w - eb4.w;
                d[j] = ((t0 * t0 + t1 * t1) + (t2 * t2 + t3 * t3)) +
                       ((t4 * t4 + t5 * t5) + (t6 * t6 + t7 * t7));
            }
            #pragma unroll
            for (int off = 1; off <= 8; off <<= 1) {
                #pragma unroll
                for (int j = 0; j < 4; ++j) d[j] += __shfl_xor(d[j], off);
            }

            int win = ci[0];
            float dw = d[0];
            #pragma unroll
            for (int j = 1; j < 4; ++j) {
                bool b = (d[j] < dw) || (d[j] == dw && ci[j] < win);
                dw = b ? d[j] : dw;
                win = b ? ci[j] : win;
            }
            if (sub == 0) winS[lrow] = win;
        }
    }
    __syncthreads();  // S2: winS visible

    // ---- hist atomics + ind + win writes ----
    if (tid < 128) {
        int w = winS[tid];
        atomicAdd(&hist[w], 1u);
        win_g[row0 + tid] = w;
        out[OFF_IND + row0 + tid] = (float)w;
    }

    // ---- quantize gather + coalesced write (16 rows per wave) ----
    #pragma unroll 4
    for (int i = 0; i < 16; ++i) {
        int lrow = wv * 16 + i;
        int w = winS[lrow];  // wave-uniform
        float2 v = *(const float2*)&embed[(size_t)w * DIM + lane * 2];
        *(float2*)&out[OFF_Q + (size_t)(row0 + lrow) * DIM + lane * 2] = v;
    }

    __syncthreads();  // S3: hist atomics done
    #pragma unroll
    for (int i = 0; i < 2; ++i) {
        unsigned c = hist[i * 512 + tid];
        if (c) atomicAdd(&counts[i * 512 + tid], (float)c);
    }
}

// ============ kernel 3: scan + scatter in ONE kernel ============
__global__ __launch_bounds__(1024) void k_scansort(const float* __restrict__ cs,
                                                   const int* __restrict__ win_arr,
                                                   float* __restrict__ ws,
                                                   int* __restrict__ sorted,
                                                   int* __restrict__ scode,
                                                   float* __restrict__ out) {
    __shared__ int h[KCODES];
    __shared__ int bs[KCODES];
    __shared__ int wsum[16];
    __shared__ float wtot[16];
    const float* counts = ws + WS_COUNTS;
    int* cursor = (int*)(ws + WS_IOFF);

    const int t = threadIdx.x;
    h[t] = 0;
    __syncthreads();
    const int row = blockIdx.x * 1024 + t;
    const int w = win_arr[row];
    const int r = atomicAdd(&h[w], 1);  // intra-block rank (LDS, cheap)

    // redundant global exclusive scan of counts
    const int lane = t & 63, wvi = t >> 6;
    const float cf = counts[t];
    const int c = (int)cf;
    int v = c;
    #pragma unroll
    for (int off = 1; off < 64; off <<= 1) {
        int o = __shfl_up(v, off);
        if (lane >= off) v += o;
    }
    if (lane == 63) wsum[wvi] = v;
    if (blockIdx.x == 0) {
        float ncs = cs[t] * 0.99f + 0.01f * cf;
        out[OFF_NCS + t] = ncs;
        float nf = ncs;
        #pragma unroll
        for (int off = 32; off; off >>= 1) nf += __shfl_xor(nf, off);
        if (lane == 0) wtot[wvi] = nf;
    }
    __syncthreads();  // h counts + wsum (+ wtot) ready

    int base = 0;
    for (int i = 0; i < wvi; ++i) base += wsum[i];
    const int gbase = base + v - c;  // global exclusive base for code t

    if (blockIdx.x == 0 && t == 0) {
        float tt = 0.f;
        for (int i = 0; i < 16; ++i) tt += wtot[i];
        ws[WS_TOTAL] = tt;
    }

    const int cnt = h[t];
    if (cnt) bs[t] = gbase + atomicAdd(&cursor[t], cnt);  // one global RMW per (block,code)
    __syncthreads();
    const int pos = bs[w] + r;
    sorted[pos] = row;
    scode[pos] = w;
}

// ============ kernel 4: run-length segment sum, 64-row chunks (skew-proof) ============
__global__ __launch_bounds__(256) void k_segsum(const float* __restrict__ x,
                                                const int* __restrict__ sorted,
                                                const int* __restrict__ scode,
                                                float* __restrict__ esum) {
    const int lane = threadIdx.x & 63;
    const int wv = threadIdx.x >> 6;
    const int base = blockIdx.x * 256 + wv * 64;  // 64 rows per wave
    const int l15 = lane & 15;

    float ax = 0.f, ay = 0.f;
    int cur = -1;

    #pragma unroll
    for (int cc = 0; cc < 4; ++cc) {
        const int p = base + cc * 16 + l15;
        const int srow = sorted[p];
        const int sc = scode[p];
        if (cc == 0) cur = __shfl(sc, 0);
        #pragma unroll
        for (int j = 0; j < 16; ++j) {
            int row = __shfl(srow, j);
            int c = __shfl(sc, j);
            if (c != cur) {
                atomicAdd(&esum[cur * DIM + lane * 2], ax);
                atomicAdd(&esum[cur * DIM + lane * 2 + 1], ay);
                ax = 0.f; ay = 0.f;
                cur = c;
            }
            float2 v = *(const float2*)&x[(size_t)row * DIM + lane * 2];
            ax += v.x;
            ay += v.y;
        }
    }
    atomicAdd(&esum[cur * DIM + lane * 2], ax);
    atomicAdd(&esum[cur * DIM + lane * 2 + 1], ay);
}

// ============ kernel 5: new_embed_avg + new_embed ============
__global__ __launch_bounds__(256) void k_embed(const float* __restrict__ ea,
                                               const float* __restrict__ ws,
                                               float* __restrict__ out) {
    int i = blockIdx.x * 256 + threadIdx.x;
    int k = i >> 7;
    float nea = ea[i] * 0.99f + 0.01f * ws[WS_ESUM + i];
    out[OFF_NEA + i] = nea;
    float total = ws[WS_TOTAL];
    float ncs = out[OFF_NCS + k];
    float sm = (ncs + 1e-5f) / (total + 1024.0f * 1e-5f);
    out[OFF_NE + i] = nea / (sm * total);
}

extern "C" void kernel_launch(void* const* d_in, const int* in_sizes, int n_in,
                              void* d_out, int out_size, void* d_ws, size_t ws_size,
                              hipStream_t stream) {
    const float* x     = (const float*)d_in[0];
    const float* embed = (const float*)d_in[1];
    const float* cs    = (const float*)d_in[2];
    const float* ea    = (const float*)d_in[3];
    float* out = (float*)d_out;
    float* ws  = (float*)d_ws;

    k_prep<<<KCODES, 64, 0, stream>>>(embed, (unsigned short*)(ws + WS_EBF),
                                      ws + WS_ENORM2, ws + WS_COUNTS, ws + WS_ESUM,
                                      (int*)(ws + WS_IOFF));
    k_fused<<<NROWS / 128, 512, 0, stream>>>(x, embed,
                                             (const unsigned short*)(ws + WS_EBF),
                                             ws + WS_ENORM2, (int*)(ws + WS_WIN),
                                             ws + WS_COUNTS, out);
    k_scansort<<<NROWS / 1024, 1024, 0, stream>>>(cs, (const int*)(ws + WS_WIN), ws,
                                                  (int*)(ws + WS_SORTED),
                                                  (int*)(ws + WS_SCODE), out);
    k_segsum<<<NROWS / 256, 256, 0, stream>>>(x, (const int*)(ws + WS_SORTED),
                                              (const int*)(ws + WS_SCODE), ws + WS_ESUM);
    k_embed<<<131072 / 256, 256, 0, stream>>>(ea, ws, out);
}

// Round 12
// 151.074 us; speedup vs baseline: 1.0040x; 1.0040x over previous
//
#include <hip/hip_runtime.h>
#include <math.h>

#define DIM 128
#define KCODES 1024
#define NROWS 65536

typedef short bf16x8 __attribute__((ext_vector_type(8)));
typedef float f32x4 __attribute__((ext_vector_type(4)));

// ---- workspace float-index layout ----
#define WS_COUNTS 0        // 1024 f: batch histogram (zeroed by k_prep)
#define WS_ESUM   1024     // 131072 f: segment sums (zeroed by k_prep)
#define WS_IOFF   132096   // 1024 int: per-code allocation cursor (zeroed by k_prep)
#define WS_TOTAL  133120   // 1 f
#define WS_ENORM2 133124   // 1024 f: 512 - 0.5*||e||^2
#define WS_EBF    134148   // 131072 bf16 (= 65536 float slots), 16B aligned, PRE-SWIZZLED
#define WS_WIN    461828   // 65536 int
#define WS_SORTED 527364   // 65536 int
#define WS_SCODE  592900   // 65536 int

// ---- output float layout ----
#define OFF_Q   0
#define OFF_IND 8388608
#define OFF_NCS 8454144
#define OFF_NEA 8455168
#define OFF_NE  8586240

// Round-12: T4 counted-vmcnt pipeline in k_fused. The per-ct __syncthreads()
// compiled to s_waitcnt vmcnt(0) (full DMA drain) -- the one catalog technique
// untried here. Now: 16 tiles x 64 codes, 4 x 16KB LDS pages, prefetch depth 3,
// loop waits vmcnt(4) (2 tiles stay in flight) + raw s_barrier; vmcnt reaches 0
// only in the epilogue ramp-down. vmcnt bookkeeping exact: two __syncthreads
// before the first DMA issue force vmcnt=0 and the loop has no other VMEM ops.
// Buffer reuse distance 4 >= depth 3 -> no race.

static __device__ __forceinline__ unsigned short f2bf(float f) {
    unsigned u = __float_as_uint(f);
    unsigned r = (u + 0x7FFFu + ((u >> 16) & 1u)) >> 16;  // RTN-even
    return (unsigned short)r;
}

// direct global->LDS DMA, 16B per lane (dest = wave-uniform base + lane*16)
static __device__ __forceinline__ void gload_lds16(const unsigned short* g,
                                                   unsigned short* l) {
    __builtin_amdgcn_global_load_lds(
        (const __attribute__((address_space(1))) void*)g,
        (__attribute__((address_space(3))) void*)l, 16, 0, 0);
}

// ============ kernel 1: embed -> PRE-SWIZZLED bf16 copy + half-norms + zeroing ============
__global__ __launch_bounds__(64) void k_prep(const float* __restrict__ embed,
                                             unsigned short* __restrict__ ebf,
                                             float* __restrict__ en2,
                                             float* __restrict__ counts,
                                             float* __restrict__ esum,
                                             int* __restrict__ cursor) {
    int k = blockIdx.x;
    int l = threadIdx.x;
    if (l == 0) { counts[k] = 0.0f; cursor[k] = 0; }
    *(float2*)&esum[(size_t)k * DIM + l * 2] = (float2){0.0f, 0.0f};
    float2 v = *(const float2*)&embed[(size_t)k * DIM + l * 2];
    ushort2 b;
    b.x = f2bf(v.x);
    b.y = f2bf(v.y);
    *(ushort2*)&ebf[(k * DIM + l * 2) ^ ((k & 7) << 3)] = b;
    float s = v.x * v.x + v.y * v.y;
    #pragma unroll
    for (int off = 32; off; off >>= 1) s += __shfl_xor(s, off);
    if (l == 0) en2[k] = 512.0f - 0.5f * s;
}

// ============ kernel 2: fused scoring + rescore + hist + quantize ============
__global__ __launch_bounds__(512, 4) void k_fused(const float* __restrict__ x,
                                                  const float* __restrict__ embed,
                                                  const unsigned short* __restrict__ ebf,
                                                  const float* __restrict__ en2g,
                                                  int* __restrict__ win_g,
                                                  float* __restrict__ counts,
                                                  float* __restrict__ out) {
    // 64KB union: x tile stages into pages 0-1; then 4 x 16KB e-tile pages;
    // epilogue scratch/hist in bytes [0,6KB).
    __shared__ unsigned short buf[32768];
    __shared__ float en2s[KCODES];
    __shared__ int winS[128];

    const int tid = threadIdx.x;  // 0..511
    const int row0 = blockIdx.x * 128;

    #pragma unroll
    for (int i = 0; i < 2; ++i) en2s[i * 512 + tid] = en2g[i * 512 + tid];

    // ---- stage x tile (fp32 -> bf16) into buf[0..16384), swizzled ----
    #pragma unroll
    for (int i = 0; i < 8; ++i) {
        int idx4 = i * 512 + tid;
        int lin = idx4 * 4;
        int r = lin >> 7, d = lin & 127;
        float4 v = *(const float4*)&x[(size_t)(row0 + r) * DIM + d];
        ushort4 b;
        b.x = f2bf(v.x); b.y = f2bf(v.y); b.z = f2bf(v.z); b.w = f2bf(v.w);
        *(ushort4*)&buf[(r * 128 + d) ^ ((r & 7) << 3)] = b;
    }
    __syncthreads();  // x tile visible (also drains vmcnt to 0)

    const int lane = tid & 63;
    const int wv = tid >> 6;        // 0..7
    const int ch = wv & 1;          // code half within tile (32 codes)
    const int rh = (wv >> 1) * 32;  // row base (32 rows per wave)
    const int l15 = lane & 15;
    const int q = lane >> 4;
    const int swz = (l15 & 7) << 3;  // fragment-row swizzle

    // ---- hoist A-fragments (ct-invariant) from buf[0..16384) ----
    bf16x8 af[4][2];  // [ks][rt]
    #pragma unroll
    for (int ks = 0; ks < 4; ++ks)
        #pragma unroll
        for (int t = 0; t < 2; ++t)
            af[ks][t] = *(const bf16x8*)&buf[((rh + t * 16 + l15) * 128 + ks * 32 + q * 8) ^ swz];
    __syncthreads();  // all af reads done; buf pages may be overwritten.
                      // vmcnt == 0 here (both barriers drained all VMEM).

    // ---- prologue: issue DMA for tiles 0,1,2 (2 loads/wave/tile) ----
    #pragma unroll
    for (int t = 0; t < 3; ++t) {
        #pragma unroll
        for (int i = 0; i < 2; ++i) {
            int idx8 = i * 512 + tid;
            gload_lds16(&ebf[t * 8192 + idx8 * 8], &buf[t * 8192 + idx8 * 8]);
        }
    }
    // wait until tile0's 2 loads (oldest) complete; tiles 1,2 stay in flight
    asm volatile("s_waitcnt vmcnt(4)" ::: "memory");
    __builtin_amdgcn_s_barrier();

    float m1[2][4], m2[2][4];
    #pragma unroll
    for (int a = 0; a < 2; ++a)
        #pragma unroll
        for (int b = 0; b < 4; ++b) { m1[a][b] = 0.0f; m2[a][b] = 0.0f; }

    for (int ct = 0; ct < 16; ++ct) {
        const int c0 = ct * 64;
        const unsigned short* cbuf = &buf[(ct & 3) * 8192];  // tile ct lives here

        // issue DMA for tile ct+3 into its page (reuse distance 4 > depth 3)
        if (ct <= 12) {
            const int tn = ct + 3;
            unsigned short* nbuf = &buf[(tn & 3) * 8192];
            const unsigned short* gsrc = &ebf[tn * 8192];
            #pragma unroll
            for (int i = 0; i < 2; ++i) {
                int idx8 = i * 512 + tid;
                gload_lds16(&gsrc[idx8 * 8], &nbuf[idx8 * 8]);
            }
        }

        // C-init = en2 (folds norm add into MFMA)
        f32x4 acc[2][2];
        #pragma unroll
        for (int cl = 0; cl < 2; ++cl) {
            float en = en2s[c0 + ch * 32 + cl * 16 + l15];
            #pragma unroll
            for (int rt = 0; rt < 2; ++rt) acc[rt][cl] = (f32x4){en, en, en, en};
        }

        __builtin_amdgcn_s_setprio(1);
        #pragma unroll
        for (int ks = 0; ks < 4; ++ks) {
            bf16x8 bfr[2];
            #pragma unroll
            for (int cl = 0; cl < 2; ++cl)
                bfr[cl] = *(const bf16x8*)&cbuf[((ch * 32 + cl * 16 + l15) * 128 + ks * 32 + q * 8) ^ swz];
            #pragma unroll
            for (int rt = 0; rt < 2; ++rt)
                #pragma unroll
                for (int cl = 0; cl < 2; ++cl)
                    acc[rt][cl] = __builtin_amdgcn_mfma_f32_16x16x32_bf16(af[ks][rt], bfr[cl],
                                                                          acc[rt][cl], 0, 0, 0);
        }

        // pairwise top-2 tracking: 5 ops / 2 values (cl=0 with cl=1)
        {
            unsigned cu0 = (unsigned)(c0 + ch * 32 + l15);
            unsigned cu1 = cu0 + 16u;
            #pragma unroll
            for (int rt = 0; rt < 2; ++rt)
                #pragma unroll
                for (int rg = 0; rg < 4; ++rg) {
                    float sa = acc[rt][0][rg];
                    float sb = acc[rt][1][rg];
                    float a = __uint_as_float((__float_as_uint(sa) & ~1023u) | cu0);
                    float b = __uint_as_float((__float_as_uint(sb) & ~1023u) | cu1);
                    m2[rt][rg] = fmaxf(m2[rt][rg],
                                       __builtin_amdgcn_fmed3f(a, b, m1[rt][rg]));
                    m1[rt][rg] = fmaxf(fmaxf(a, b), m1[rt][rg]);
                }
        }
        __builtin_amdgcn_s_setprio(0);

        // counted wait: next tile (ct+1) drained, deeper prefetch stays in flight
        if (ct < 15) {
            if (ct < 13) {
                asm volatile("s_waitcnt vmcnt(4)" ::: "memory");
            } else if (ct == 13) {
                asm volatile("s_waitcnt vmcnt(2)" ::: "memory");
            } else {
                asm volatile("s_waitcnt vmcnt(0)" ::: "memory");
            }
            __builtin_amdgcn_s_barrier();
        }
    }

    // buf free: floats [0,512) = merge scratch, [512,1536) = histogram
    // (bytes [0,6144) -- disjoint from tile-3 page [49152,65536) still being read)
    float* scratch = (float*)buf;
    unsigned* hist = (unsigned*)buf + 512;

    #pragma unroll
    for (int rt = 0; rt < 2; ++rt)
        #pragma unroll
        for (int rg = 0; rg < 4; ++rg) {
            float a1 = m1[rt][rg], a2 = m2[rt][rg];
            #pragma unroll
            for (int off = 1; off <= 8; off <<= 1) {
                float o1 = __shfl_xor(a1, off);
                float o2 = __shfl_xor(a2, off);
                float t = fmaxf(a2, o2);
                a2 = __builtin_amdgcn_fmed3f(a1, o1, t);
                a1 = fmaxf(a1, o1);
            }
            if (l15 == 0) {
                int row = rh + rt * 16 + q * 4 + rg;
                scratch[row * 4 + ch * 2 + 0] = a1;
                scratch[row * 4 + ch * 2 + 1] = a2;
            }
        }

    #pragma unroll
    for (int i = 0; i < 2; ++i) hist[i * 512 + tid] = 0u;
    __syncthreads();  // S1: scratch + hist-zero visible

    // ---- fp32 exact-difference rescore: 16 lanes/row ----
    {
        const int sub = tid & 15;
        const int g = tid >> 4;  // 0..31
        #pragma unroll 2
        for (int rr = 0; rr < 4; ++rr) {
            const int lrow = g * 4 + rr;
            const float* sp = &scratch[lrow * 4];
            int ci[4];
            ci[0] = (int)(__float_as_uint(sp[0]) & 1023u);
            ci[1] = (int)(__float_as_uint(sp[1]) & 1023u);
            ci[2] = (int)(__float_as_uint(sp[2]) & 1023u);
            ci[3] = (int)(__float_as_uint(sp[3]) & 1023u);

            const float* xr = &x[(size_t)(row0 + lrow) * DIM + sub * 4];
            float4 xa = *(const float4*)xr;
            float4 xb = *(const float4*)(xr + 64);

            float d[4];
            #pragma unroll
            for (int j = 0; j < 4; ++j) {
                const float* er2 = &embed[(size_t)ci[j] * DIM + sub * 4];
                float4 ea4 = *(const float4*)er2;
                float4 eb4 = *(const float4*)(er2 + 64);
                float t0 = xa.x - ea4.x;
                float t1 = xa.y - ea4.y;
                float t2 = xa.z - ea4.z;
                float t3 = xa.w - ea4.w;
                float t4 = xb.x - eb4.x;
                float t5 = xb.y - eb4.y;
                float t6 = xb.z - eb4.z;
                float t7 = xb.w - eb4.w;
                d[j] = ((t0 * t0 + t1 * t1) + (t2 * t2 + t3 * t3)) +
                       ((t4 * t4 + t5 * t5) + (t6 * t6 + t7 * t7));
            }
            #pragma unroll
            for (int off = 1; off <= 8; off <<= 1) {
                #pragma unroll
                for (int j = 0; j < 4; ++j) d[j] += __shfl_xor(d[j], off);
            }

            int win = ci[0];
            float dw = d[0];
            #pragma unroll
            for (int j = 1; j < 4; ++j) {
                bool b = (d[j] < dw) || (d[j] == dw && ci[j] < win);
                dw = b ? d[j] : dw;
                win = b ? ci[j] : win;
            }
            if (sub == 0) winS[lrow] = win;
        }
    }
    __syncthreads();  // S2: winS visible

    // ---- hist atomics + ind + win writes ----
    if (tid < 128) {
        int w = winS[tid];
        atomicAdd(&hist[w], 1u);
        win_g[row0 + tid] = w;
        out[OFF_IND + row0 + tid] = (float)w;
    }

    // ---- quantize gather + coalesced write (16 rows per wave) ----
    #pragma unroll 4
    for (int i = 0; i < 16; ++i) {
        int lrow = wv * 16 + i;
        int w = winS[lrow];  // wave-uniform
        float2 v = *(const float2*)&embed[(size_t)w * DIM + lane * 2];
        *(float2*)&out[OFF_Q + (size_t)(row0 + lrow) * DIM + lane * 2] = v;
    }

    __syncthreads();  // S3: hist atomics done
    #pragma unroll
    for (int i = 0; i < 2; ++i) {
        unsigned c = hist[i * 512 + tid];
        if (c) atomicAdd(&counts[i * 512 + tid], (float)c);
    }
}

// ============ kernel 3: scan + scatter in ONE kernel ============
__global__ __launch_bounds__(1024) void k_scansort(const float* __restrict__ cs,
                                                   const int* __restrict__ win_arr,
                                                   float* __restrict__ ws,
                                                   int* __restrict__ sorted,
                                                   int* __restrict__ scode,
                                                   float* __restrict__ out) {
    __shared__ int h[KCODES];
    __shared__ int bs[KCODES];
    __shared__ int wsum[16];
    __shared__ float wtot[16];
    const float* counts = ws + WS_COUNTS;
    int* cursor = (int*)(ws + WS_IOFF);

    const int t = threadIdx.x;
    h[t] = 0;
    __syncthreads();
    const int row = blockIdx.x * 1024 + t;
    const int w = win_arr[row];
    const int r = atomicAdd(&h[w], 1);  // intra-block rank (LDS, cheap)

    // redundant global exclusive scan of counts
    const int lane = t & 63, wvi = t >> 6;
    const float cf = counts[t];
    const int c = (int)cf;
    int v = c;
    #pragma unroll
    for (int off = 1; off < 64; off <<= 1) {
        int o = __shfl_up(v, off);
        if (lane >= off) v += o;
    }
    if (lane == 63) wsum[wvi] = v;
    if (blockIdx.x == 0) {
        float ncs = cs[t] * 0.99f + 0.01f * cf;
        out[OFF_NCS + t] = ncs;
        float nf = ncs;
        #pragma unroll
        for (int off = 32; off; off >>= 1) nf += __shfl_xor(nf, off);
        if (lane == 0) wtot[wvi] = nf;
    }
    __syncthreads();  // h counts + wsum (+ wtot) ready

    int base = 0;
    for (int i = 0; i < wvi; ++i) base += wsum[i];
    const int gbase = base + v - c;  // global exclusive base for code t

    if (blockIdx.x == 0 && t == 0) {
        float tt = 0.f;
        for (int i = 0; i < 16; ++i) tt += wtot[i];
        ws[WS_TOTAL] = tt;
    }

    const int cnt = h[t];
    if (cnt) bs[t] = gbase + atomicAdd(&cursor[t], cnt);  // one global RMW per (block,code)
    __syncthreads();
    const int pos = bs[w] + r;
    sorted[pos] = row;
    scode[pos] = w;
}

// ============ kernel 4: run-length segment sum, 64-row chunks (skew-proof) ============
__global__ __launch_bounds__(256) void k_segsum(const float* __restrict__ x,
                                                const int* __restrict__ sorted,
                                                const int* __restrict__ scode,
                                                float* __restrict__ esum) {
    const int lane = threadIdx.x & 63;
    const int wv = threadIdx.x >> 6;
    const int base = blockIdx.x * 256 + wv * 64;  // 64 rows per wave
    const int l15 = lane & 15;

    float ax = 0.f, ay = 0.f;
    int cur = -1;

    #pragma unroll
    for (int cc = 0; cc < 4; ++cc) {
        const int p = base + cc * 16 + l15;
        const int srow = sorted[p];
        const int sc = scode[p];
        if (cc == 0) cur = __shfl(sc, 0);
        #pragma unroll
        for (int j = 0; j < 16; ++j) {
            int row = __shfl(srow, j);
            int c = __shfl(sc, j);
            if (c != cur) {
                atomicAdd(&esum[cur * DIM + lane * 2], ax);
                atomicAdd(&esum[cur * DIM + lane * 2 + 1], ay);
                ax = 0.f; ay = 0.f;
                cur = c;
            }
            float2 v = *(const float2*)&x[(size_t)row * DIM + lane * 2];
            ax += v.x;
            ay += v.y;
        }
    }
    atomicAdd(&esum[cur * DIM + lane * 2], ax);
    atomicAdd(&esum[cur * DIM + lane * 2 + 1], ay);
}

// ============ kernel 5: new_embed_avg + new_embed ============
__global__ __launch_bounds__(256) void k_embed(const float* __restrict__ ea,
                                               const float* __restrict__ ws,
                                               float* __restrict__ out) {
    int i = blockIdx.x * 256 + threadIdx.x;
    int k = i >> 7;
    float nea = ea[i] * 0.99f + 0.01f * ws[WS_ESUM + i];
    out[OFF_NEA + i] = nea;
    float total = ws[WS_TOTAL];
    float ncs = out[OFF_NCS + k];
    float sm = (ncs + 1e-5f) / (total + 1024.0f * 1e-5f);
    out[OFF_NE + i] = nea / (sm * total);
}

extern "C" void kernel_launch(void* const* d_in, const int* in_sizes, int n_in,
                              void* d_out, int out_size, void* d_ws, size_t ws_size,
                              hipStream_t stream) {
    const float* x     = (const float*)d_in[0];
    const float* embed = (const float*)d_in[1];
    const float* cs    = (const float*)d_in[2];
    const float* ea    = (const float*)d_in[3];
    float* out = (float*)d_out;
    float* ws  = (float*)d_ws;

    k_prep<<<KCODES, 64, 0, stream>>>(embed, (unsigned short*)(ws + WS_EBF),
                                      ws + WS_ENORM2, ws + WS_COUNTS, ws + WS_ESUM,
                                      (int*)(ws + WS_IOFF));
    k_fused<<<NROWS / 128, 512, 0, stream>>>(x, embed,
                                             (const unsigned short*)(ws + WS_EBF),
                                             ws + WS_ENORM2, (int*)(ws + WS_WIN),
                                             ws + WS_COUNTS, out);
    k_scansort<<<NROWS / 1024, 1024, 0, stream>>>(cs, (const int*)(ws + WS_WIN), ws,
                                                  (int*)(ws + WS_SORTED),
                                                  (int*)(ws + WS_SCODE), out);
    k_segsum<<<NROWS / 256, 256, 0, stream>>>(x, (const int*)(ws + WS_SORTED),
                                              (const int*)(ws + WS_SCODE), ws + WS_ESUM);
    k_embed<<<131072 / 256, 256, 0, stream>>>(ea, ws, out);
}